// Round 14
// baseline (1049.239 us; speedup 1.0000x reference)
//
#include <hip/hip_runtime.h>

#define NN 100000
#define DD 128
#define RR 4
#define EE 150000
#define HH 8
#define DK 16

#define NSEG (RR * NN)        // 400000
#define NEDGE (RR * EE)       // 600000
#define SCAN_BLK 256
#define SCAN_ELEMS 1024
#define SCAN_NB ((NSEG + SCAN_ELEMS - 1) / SCAN_ELEMS)   // 391
#define PAD_K 136             // bf16 row stride for MFMA LDS tiles
#define MAT_U 132             // uints per 16x16 bf16 matrix (528 B stride)
#define ND2 (NN * 64)         // uints per packed bf16 [node][128] buffer
#define WMAT 8192             // uints per packed 128x128 bf16 weight matrix

typedef short bf16x8 __attribute__((ext_vector_type(8)));
typedef float f32x4  __attribute__((ext_vector_type(4)));

// f32 -> bf16 round-to-nearest-even (bit pattern as ushort)
__device__ __forceinline__ unsigned short f2bf(float f) {
    unsigned u = __float_as_uint(f);
    return (unsigned short)((u + 0x7fffu + ((u >> 16) & 1u)) >> 16);
}
__device__ __forceinline__ float bflo(unsigned w) { return __uint_as_float(w << 16); }
__device__ __forceinline__ float bfhi(unsigned w) { return __uint_as_float(w & 0xffff0000u); }

// fragment-order swizzle for packed W: uint (n,c) -> position such that the
// wave-load of fragment (wc,j,ks) is lane-contiguous (fully coalesced).
__device__ __forceinline__ int wswz(int n, int c) {
    int ks = c >> 4, kg = (c >> 2) & 3, e = c & 3;
    int wc = n >> 6, j = (n >> 4) & 3, lrow = n & 15;
    return ((((ks * 2 + wc) * 4 + j) * 64) + kg * 16 + lrow) * 4 + e;
}

// ---------- prep: pack Wk, Wq to swizzled bf16; copy biases ----------
__global__ __launch_bounds__(256) void prep_pack(
    const float* __restrict__ Wk, const float* __restrict__ bk,
    const float* __restrict__ Wq, const float* __restrict__ bq,
    unsigned* __restrict__ wAll, float* __restrict__ bAll)
{
    const int b = blockIdx.x;   // 0: k, 1: q
    const float* W = b ? Wq : Wk;
    const float* bias = b ? bq : bk;
    unsigned* out = wAll + b * WMAT;
    const int tid = threadIdx.x;
    #pragma unroll
    for (int i = 0; i < 32; ++i) {
        int idx = tid + 256 * i;                    // 0..8191 = n*64 + c
        float2 v = *(const float2*)(W + idx * 2);
        unsigned u = (unsigned)f2bf(v.x) | ((unsigned)f2bf(v.y) << 16);
        out[wswz(idx >> 6, idx & 63)] = u;
    }
    if (tid < 128) bAll[b * 128 + tid] = bias[tid];
}

// ---------- prep: W_msg[r] = rel_msg-combined Wv (swizzled bf16), b_msg ----------
// W_msg[r][h*16+f][c] = sum_d M[r,h][d][f] * Wv[h*16+d][c]
__global__ __launch_bounds__(128) void prep_wmsg(
    const float* __restrict__ Wv, const float* __restrict__ bv,
    const float* __restrict__ rel_msg,
    unsigned* __restrict__ wAll, float* __restrict__ bAll)
{
    const int b = blockIdx.x;          // r*8 + h
    const int r = b >> 3, h = b & 7;
    const int c = threadIdx.x;         // 0..127
    __shared__ float Msh[256];
    __shared__ float sh2[16][128];
    for (int i = c; i < 256; i += 128) Msh[i] = rel_msg[(b << 8) + i];
    __syncthreads();

    #pragma unroll 4
    for (int f = 0; f < 16; ++f) {
        float acc = 0.f;
        #pragma unroll
        for (int d = 0; d < 16; ++d)
            acc = __builtin_fmaf(Msh[d * 16 + f], Wv[(h * 16 + d) * DD + c], acc);
        sh2[f][c] = acc;
    }
    if (c < 16) {
        float acc = 0.f;
        #pragma unroll
        for (int d = 0; d < 16; ++d)
            acc = __builtin_fmaf(Msh[d * 16 + c], bv[h * 16 + d], acc);
        bAll[(2 + r) * 128 + h * 16 + c] = acc;
    }
    __syncthreads();

    unsigned* out = wAll + (2 + r) * WMAT;
    #pragma unroll
    for (int k = 0; k < 8; ++k) {
        int idx = c * 8 + k;            // 0..1023
        int f = idx >> 6, jc = idx & 63;
        unsigned u = (unsigned)f2bf(sh2[f][2 * jc]) | ((unsigned)f2bf(sh2[f][2 * jc + 1]) << 16);
        out[wswz(h * 16 + f, jc)] = u;
    }
}

// ---------- MFMA projections (grid.y = 3, TWO mats per block) ----------
__global__ __launch_bounds__(256) void mfma_proj(
    const float* __restrict__ X,
    const unsigned* __restrict__ wAll, const float* __restrict__ bAll,
    unsigned* __restrict__ kb, unsigned* __restrict__ qb, unsigned* __restrict__ vMb)
{
    const int tid = threadIdx.x;
    const int lane = tid & 63;
    const int wave = tid >> 6;
    const int wr = wave >> 1;            // X-row half (32 rows)
    const int wc = wave & 1;             // out-dim half (64 dims)
    const long m0 = (long)blockIdx.x * 64;
    const int mp = blockIdx.y * 2;       // first of the 2 mats

    __shared__ short Xs[64 * PAD_K];

    #pragma unroll
    for (int i = 0; i < 8; ++i) {
        int f = tid + 256 * i;
        int row = f >> 5, c4 = f & 31;
        long m = m0 + row;
        float4 v = make_float4(0.f, 0.f, 0.f, 0.f);
        if (m < NN) v = ((const float4*)(X + m * DD))[c4];
        unsigned u0 = (unsigned)f2bf(v.x) | ((unsigned)f2bf(v.y) << 16);
        unsigned u1 = (unsigned)f2bf(v.z) | ((unsigned)f2bf(v.w) << 16);
        *(uint2*)&Xs[row * PAD_K + c4 * 4] = make_uint2(u0, u1);
    }
    __syncthreads();

    const int lrow = lane & 15;
    const int kg = lane >> 4;            // 0..3

    #pragma unroll
    for (int mm = 0; mm < 2; ++mm) {
        const int mat = mp + mm;
        const unsigned* Wp = wAll + mat * WMAT;
        const float* bias = bAll + mat * 128;
        unsigned* outb = (mat == 0) ? kb : (mat == 1) ? qb : (vMb + (long)(mat - 2) * ND2);

        f32x4 acc[2][4];
        #pragma unroll
        for (int i = 0; i < 2; ++i)
            #pragma unroll
            for (int j = 0; j < 4; ++j) acc[i][j] = (f32x4){0.f, 0.f, 0.f, 0.f};

        #pragma unroll
        for (int ks = 0; ks < 4; ++ks) {
            const int kk = ks * 32 + kg * 8;
            bf16x8 xf[2], wf[4];
            #pragma unroll
            for (int i = 0; i < 2; ++i)
                xf[i] = *(const bf16x8*)&Xs[(wr * 32 + i * 16 + lrow) * PAD_K + kk];
            #pragma unroll
            for (int j = 0; j < 4; ++j)
                wf[j] = *(const bf16x8*)(Wp + (((ks * 2 + wc) * 4 + j) << 8) + (lane << 2));
            #pragma unroll
            for (int i = 0; i < 2; ++i)
                #pragma unroll
                for (int j = 0; j < 4; ++j)
                    acc[i][j] = __builtin_amdgcn_mfma_f32_16x16x32_bf16(wf[j], xf[i], acc[i][j], 0, 0, 0);
        }

        #pragma unroll
        for (int j = 0; j < 4; ++j) {
            const int nb = wc * 64 + j * 16 + kg * 4;
            const float b0 = bias[nb + 0], b1 = bias[nb + 1];
            const float b2 = bias[nb + 2], b3 = bias[nb + 3];
            #pragma unroll
            for (int i = 0; i < 2; ++i) {
                long m = m0 + wr * 32 + i * 16 + lrow;
                if (m < NN) {
                    unsigned u0 = (unsigned)f2bf(acc[i][j][0] + b0) | ((unsigned)f2bf(acc[i][j][1] + b1) << 16);
                    unsigned u1 = (unsigned)f2bf(acc[i][j][2] + b2) | ((unsigned)f2bf(acc[i][j][3] + b3) << 16);
                    *(uint2*)&outb[m * 64 + (nb >> 1)] = make_uint2(u0, u1);
                }
            }
        }
    }
}

// ---------- MFMA bf16 output GEMM: out = tb@Wa^T + ba, skip-gated ----------
__global__ __launch_bounds__(256) void mfma_out(
    const unsigned* __restrict__ Tp, const float* __restrict__ Wa, const float* __restrict__ ba,
    float* __restrict__ out, const float* __restrict__ skip, const float* __restrict__ xres)
{
    const int tid = threadIdx.x;
    const int lane = tid & 63;
    const int wave = tid >> 6;
    const int wr = wave >> 1;
    const int wc = wave & 1;
    const long m0 = (long)blockIdx.x * 64;

    __shared__ short Xs[64 * PAD_K];
    __shared__ short Wsh[128 * PAD_K];

    #pragma unroll
    for (int i = 0; i < 4; ++i) {
        int f = tid + 256 * i;            // uint4 slot in 64x16
        int row = f >> 4, c = f & 15;
        long m = m0 + row;
        uint4 v = make_uint4(0u, 0u, 0u, 0u);
        if (m < NN) v = ((const uint4*)(Tp + m * 64))[c];
        *(uint4*)&Xs[row * PAD_K + c * 8] = v;
    }
    #pragma unroll
    for (int i = 0; i < 16; ++i) {
        int f = tid + 256 * i;
        int row = f >> 5, c4 = f & 31;
        float4 v = ((const float4*)(Wa + row * DD))[c4];
        unsigned u0 = (unsigned)f2bf(v.x) | ((unsigned)f2bf(v.y) << 16);
        unsigned u1 = (unsigned)f2bf(v.z) | ((unsigned)f2bf(v.w) << 16);
        *(uint2*)&Wsh[row * PAD_K + c4 * 4] = make_uint2(u0, u1);
    }
    __syncthreads();

    const int lrow = lane & 15;
    const int kg = lane >> 4;

    f32x4 acc[2][4];
    #pragma unroll
    for (int i = 0; i < 2; ++i)
        #pragma unroll
        for (int j = 0; j < 4; ++j) acc[i][j] = (f32x4){0.f, 0.f, 0.f, 0.f};

    #pragma unroll
    for (int ks = 0; ks < 4; ++ks) {
        const int kk = ks * 32 + kg * 8;
        bf16x8 xf[2], wf[4];
        #pragma unroll
        for (int i = 0; i < 2; ++i)
            xf[i] = *(const bf16x8*)&Xs[(wr * 32 + i * 16 + lrow) * PAD_K + kk];
        #pragma unroll
        for (int j = 0; j < 4; ++j)
            wf[j] = *(const bf16x8*)&Wsh[(wc * 64 + j * 16 + lrow) * PAD_K + kk];
        #pragma unroll
        for (int i = 0; i < 2; ++i)
            #pragma unroll
            for (int j = 0; j < 4; ++j)
                acc[i][j] = __builtin_amdgcn_mfma_f32_16x16x32_bf16(xf[i], wf[j], acc[i][j], 0, 0, 0);
    }

    const float s = 1.f / (1.f + __expf(-skip[0]));
    const float al = s, bt = 1.f - s;

    #pragma unroll
    for (int j = 0; j < 4; ++j) {
        const int n = wc * 64 + j * 16 + lrow;
        const float bcol = ba[n];
        #pragma unroll
        for (int i = 0; i < 2; ++i) {
            #pragma unroll
            for (int r = 0; r < 4; ++r) {
                long m = m0 + wr * 32 + i * 16 + kg * 4 + r;
                if (m < NN) {
                    long o = m * DD + n;
                    out[o] = __builtin_fmaf(xres[o], bt, (acc[i][j][r] + bcol) * al);
                }
            }
        }
    }
}

// ---------- CSR build: histogram -> scan -> fill ----------

__global__ __launch_bounds__(256) void csr_hist(
    const int* __restrict__ edst, int* __restrict__ cnt)
{
    int idx = blockIdx.x * 256 + threadIdx.x;
    if (idx >= NEDGE) return;
    int r = idx / EE;
    atomicAdd(&cnt[r * NN + edst[idx]], 1);
}

__global__ __launch_bounds__(SCAN_BLK) void scan1(
    const int* __restrict__ cnt, int* __restrict__ offs, int* __restrict__ bsum)
{
    __shared__ int sh[SCAN_BLK];
    int blk = blockIdx.x, tid = threadIdx.x;
    int base = blk * SCAN_ELEMS + tid * 4;
    int v0 = 0, v1 = 0, v2 = 0, v3 = 0;
    if (base + 3 < NSEG) {
        int4 t = *(const int4*)(cnt + base);
        v0 = t.x; v1 = t.y; v2 = t.z; v3 = t.w;
    } else {
        if (base + 0 < NSEG) v0 = cnt[base + 0];
        if (base + 1 < NSEG) v1 = cnt[base + 1];
        if (base + 2 < NSEG) v2 = cnt[base + 2];
        if (base + 3 < NSEG) v3 = cnt[base + 3];
    }
    int tsum = v0 + v1 + v2 + v3;
    sh[tid] = tsum;
    __syncthreads();
    #pragma unroll
    for (int d = 1; d < SCAN_BLK; d <<= 1) {
        int x = (tid >= d) ? sh[tid - d] : 0;
        __syncthreads();
        sh[tid] += x;
        __syncthreads();
    }
    int excl = sh[tid] - tsum;
    int r0 = excl, r1 = r0 + v0, r2 = r1 + v1, r3 = r2 + v2;
    if (base + 3 < NSEG) {
        *(int4*)(offs + base) = make_int4(r0, r1, r2, r3);
    } else {
        if (base + 0 < NSEG) offs[base + 0] = r0;
        if (base + 1 < NSEG) offs[base + 1] = r1;
        if (base + 2 < NSEG) offs[base + 2] = r2;
        if (base + 3 < NSEG) offs[base + 3] = r3;
    }
    if (tid == SCAN_BLK - 1) bsum[blk] = sh[tid];
}

__global__ __launch_bounds__(512) void scan2(int* __restrict__ bsum)
{
    __shared__ int sh[512];
    int tid = threadIdx.x;
    int v = (tid < SCAN_NB) ? bsum[tid] : 0;
    sh[tid] = v;
    __syncthreads();
    #pragma unroll
    for (int d = 1; d < 512; d <<= 1) {
        int x = (tid >= d) ? sh[tid - d] : 0;
        __syncthreads();
        sh[tid] += x;
        __syncthreads();
    }
    if (tid < SCAN_NB) bsum[tid] = sh[tid] - v;
}

__global__ __launch_bounds__(SCAN_BLK) void scan3(
    int* __restrict__ offs, int* __restrict__ cur, const int* __restrict__ bsum)
{
    int blk = blockIdx.x;
    int add = bsum[blk];
    int base = blk * SCAN_ELEMS + threadIdx.x * 4;
    #pragma unroll
    for (int j = 0; j < 4; ++j)
        if (base + j < NSEG) {
            int v = offs[base + j] + add;
            offs[base + j] = v;
            cur[base + j] = v;
        }
}

__global__ __launch_bounds__(256) void csr_fill(
    const int* __restrict__ esrc, const int* __restrict__ edst,
    int* __restrict__ cur, int* __restrict__ csr_src)
{
    int idx = blockIdx.x * 256 + threadIdx.x;
    if (idx >= NEDGE) return;
    int r = idx / EE;
    int pos = atomicAdd(&cur[r * NN + edst[idx]], 1);
    csr_src[pos] = esrc[idx];
}

// ---------- degree counting-sort: group similar-degree dsts per wave ----------
// deg = total degree across relations (clamped 1023); counting sort into
// order[]. Within-degree order is nondeterministic, but each gather thread's
// math and output location depend only on its dst -> output deterministic.
__global__ __launch_bounds__(256) void deg_hist(
    const int* __restrict__ offs, int* __restrict__ deg, int* __restrict__ dhist)
{
    int i = blockIdx.x * 256 + threadIdx.x;
    if (i >= NN) return;
    int d = 0;
    #pragma unroll
    for (int r = 0; r < RR; ++r) {
        int seg = r * NN + i;
        int beg = offs[seg];
        int end = (seg == NSEG - 1) ? NEDGE : offs[seg + 1];
        d += end - beg;
    }
    d = min(d, 1023);
    deg[i] = d;
    atomicAdd(&dhist[d], 1);
}

__global__ __launch_bounds__(1024) void deg_scan(
    const int* __restrict__ dhist, int* __restrict__ dcur)
{
    __shared__ int sh[1024];
    int tid = threadIdx.x;
    int v = dhist[tid];
    sh[tid] = v;
    __syncthreads();
    for (int d = 1; d < 1024; d <<= 1) {
        int x = (tid >= d) ? sh[tid - d] : 0;
        __syncthreads();
        sh[tid] += x;
        __syncthreads();
    }
    dcur[tid] = sh[tid] - v;   // exclusive prefix
}

__global__ __launch_bounds__(256) void deg_fill(
    const int* __restrict__ deg, int* __restrict__ dcur, int* __restrict__ order)
{
    int i = blockIdx.x * 256 + threadIdx.x;
    if (i >= NN) return;
    int pos = atomicAdd(&dcur[deg[i]], 1);
    order[pos] = i;
}

// ---------- fused per-dst gather (degree-sorted dst order) ----------
// thread = (order[i], h). A (rel_att) staged bf16 in LDS + pri.
// Per relation: qbar = A@q once; edge loop reads k 32B + vM 32B; vb
// accumulates exp(att)*vM. t written packed bf16 (0.25 folded).
#define GT 512
__global__ __launch_bounds__(GT) void gather_agg(
    const unsigned* __restrict__ kb, const unsigned* __restrict__ qbuf,
    const unsigned* __restrict__ vMb,
    const int* __restrict__ csr_src, const int* __restrict__ offs,
    const int* __restrict__ order,
    const float* __restrict__ rel_att, const float* __restrict__ rel_pri,
    unsigned* __restrict__ tb)
{
    __shared__ unsigned As[32 * MAT_U];
    __shared__ float prish[32];
    const int tid = threadIdx.x;
    #pragma unroll
    for (int i = 0; i < (32 * 128) / GT; ++i) {
        int f = tid + GT * i;
        int m = f >> 7, j = f & 127;
        float2 a = *(const float2*)(rel_att + m * 256 + j * 2);
        As[m * MAT_U + j] = (unsigned)f2bf(a.x) | ((unsigned)f2bf(a.y) << 16);
    }
    if (tid < 32) prish[tid] = rel_pri[tid] * 0.25f;
    __syncthreads();

    int gidx = blockIdx.x * GT + tid;
    if (gidx >= NN * HH) return;
    const int dst = order[gidx >> 3];
    const int h = gidx & 7;

    float qh[16];
    {
        const uint4* qp = (const uint4*)(qbuf + (long)dst * 64 + h * 8);
        uint4 qa = qp[0], qc = qp[1];
        qh[0] = bflo(qa.x);  qh[1] = bfhi(qa.x);
        qh[2] = bflo(qa.y);  qh[3] = bfhi(qa.y);
        qh[4] = bflo(qa.z);  qh[5] = bfhi(qa.z);
        qh[6] = bflo(qa.w);  qh[7] = bfhi(qa.w);
        qh[8] = bflo(qc.x);  qh[9] = bfhi(qc.x);
        qh[10] = bflo(qc.y); qh[11] = bfhi(qc.y);
        qh[12] = bflo(qc.z); qh[13] = bfhi(qc.z);
        qh[14] = bflo(qc.w); qh[15] = bfhi(qc.w);
    }

    float tacc[16];
    #pragma unroll
    for (int f = 0; f < 16; ++f) tacc[f] = 0.f;

    for (int r = 0; r < RR; ++r) {
        const int seg = r * NN + dst;
        const int beg = offs[seg];
        const int end = (seg == NSEG - 1) ? NEDGE : offs[seg + 1];
        if (end <= beg) continue;                 // empty mailbox contributes 0

        const unsigned* A = &As[(r * HH + h) * MAT_U];
        const float pri = prish[r * HH + h];

        float qbar[16];
        #pragma unroll
        for (int d = 0; d < 16; ++d) {
            uint4 r0 = *(const uint4*)&A[d * 8];
            uint4 r1 = *(const uint4*)&A[d * 8 + 4];
            float acc = bflo(r0.x) * qh[0];
            acc = __builtin_fmaf(bfhi(r0.x), qh[1], acc);
            acc = __builtin_fmaf(bflo(r0.y), qh[2], acc);
            acc = __builtin_fmaf(bfhi(r0.y), qh[3], acc);
            acc = __builtin_fmaf(bflo(r0.z), qh[4], acc);
            acc = __builtin_fmaf(bfhi(r0.z), qh[5], acc);
            acc = __builtin_fmaf(bflo(r0.w), qh[6], acc);
            acc = __builtin_fmaf(bfhi(r0.w), qh[7], acc);
            acc = __builtin_fmaf(bflo(r1.x), qh[8], acc);
            acc = __builtin_fmaf(bfhi(r1.x), qh[9], acc);
            acc = __builtin_fmaf(bflo(r1.y), qh[10], acc);
            acc = __builtin_fmaf(bfhi(r1.y), qh[11], acc);
            acc = __builtin_fmaf(bflo(r1.z), qh[12], acc);
            acc = __builtin_fmaf(bfhi(r1.z), qh[13], acc);
            acc = __builtin_fmaf(bflo(r1.w), qh[14], acc);
            acc = __builtin_fmaf(bfhi(r1.w), qh[15], acc);
            qbar[d] = acc * pri;
        }

        float s = 0.f;
        float vb[16];
        #pragma unroll
        for (int f = 0; f < 16; ++f) vb[f] = 0.f;

        const unsigned* vMr = vMb + (long)r * ND2;
        for (int e = beg; e < end; ++e) {
            int src = csr_src[e];
            const uint4* kp = (const uint4*)(kb + (long)src * 64 + h * 8);
            uint4 ka = kp[0], kc = kp[1];
            const uint4* vp = (const uint4*)(vMr + (long)src * 64 + h * 8);
            uint4 va = vp[0], vc = vp[1];

            float att;
            att  = bflo(ka.x) * qbar[0];
            att = __builtin_fmaf(bfhi(ka.x), qbar[1], att);
            att = __builtin_fmaf(bflo(ka.y), qbar[2], att);
            att = __builtin_fmaf(bfhi(ka.y), qbar[3], att);
            att = __builtin_fmaf(bflo(ka.z), qbar[4], att);
            att = __builtin_fmaf(bfhi(ka.z), qbar[5], att);
            att = __builtin_fmaf(bflo(ka.w), qbar[6], att);
            att = __builtin_fmaf(bfhi(ka.w), qbar[7], att);
            att = __builtin_fmaf(bflo(kc.x), qbar[8], att);
            att = __builtin_fmaf(bfhi(kc.x), qbar[9], att);
            att = __builtin_fmaf(bflo(kc.y), qbar[10], att);
            att = __builtin_fmaf(bfhi(kc.y), qbar[11], att);
            att = __builtin_fmaf(bflo(kc.z), qbar[12], att);
            att = __builtin_fmaf(bfhi(kc.z), qbar[13], att);
            att = __builtin_fmaf(bflo(kc.w), qbar[14], att);
            att = __builtin_fmaf(bfhi(kc.w), qbar[15], att);

            float ea = __expf(att);
            s += ea;
            vb[0]  = __builtin_fmaf(ea, bflo(va.x), vb[0]);
            vb[1]  = __builtin_fmaf(ea, bfhi(va.x), vb[1]);
            vb[2]  = __builtin_fmaf(ea, bflo(va.y), vb[2]);
            vb[3]  = __builtin_fmaf(ea, bfhi(va.y), vb[3]);
            vb[4]  = __builtin_fmaf(ea, bflo(va.z), vb[4]);
            vb[5]  = __builtin_fmaf(ea, bfhi(va.z), vb[5]);
            vb[6]  = __builtin_fmaf(ea, bflo(va.w), vb[6]);
            vb[7]  = __builtin_fmaf(ea, bfhi(va.w), vb[7]);
            vb[8]  = __builtin_fmaf(ea, bflo(vc.x), vb[8]);
            vb[9]  = __builtin_fmaf(ea, bfhi(vc.x), vb[9]);
            vb[10] = __builtin_fmaf(ea, bflo(vc.y), vb[10]);
            vb[11] = __builtin_fmaf(ea, bfhi(vc.y), vb[11]);
            vb[12] = __builtin_fmaf(ea, bflo(vc.z), vb[12]);
            vb[13] = __builtin_fmaf(ea, bfhi(vc.z), vb[13]);
            vb[14] = __builtin_fmaf(ea, bflo(vc.w), vb[14]);
            vb[15] = __builtin_fmaf(ea, bfhi(vc.w), vb[15]);
        }

        float inv = 1.f / s;
        #pragma unroll
        for (int f = 0; f < 16; ++f)
            tacc[f] = __builtin_fmaf(vb[f], inv, tacc[f]);
    }

    // write t packed bf16 with the cross-relation mean (x0.25, exact) folded
    unsigned* tp = tb + (long)dst * 64 + h * 8;
    uint4 o0, o1;
    o0.x = (unsigned)f2bf(tacc[0] * 0.25f)  | ((unsigned)f2bf(tacc[1] * 0.25f) << 16);
    o0.y = (unsigned)f2bf(tacc[2] * 0.25f)  | ((unsigned)f2bf(tacc[3] * 0.25f) << 16);
    o0.z = (unsigned)f2bf(tacc[4] * 0.25f)  | ((unsigned)f2bf(tacc[5] * 0.25f) << 16);
    o0.w = (unsigned)f2bf(tacc[6] * 0.25f)  | ((unsigned)f2bf(tacc[7] * 0.25f) << 16);
    o1.x = (unsigned)f2bf(tacc[8] * 0.25f)  | ((unsigned)f2bf(tacc[9] * 0.25f) << 16);
    o1.y = (unsigned)f2bf(tacc[10] * 0.25f) | ((unsigned)f2bf(tacc[11] * 0.25f) << 16);
    o1.z = (unsigned)f2bf(tacc[12] * 0.25f) | ((unsigned)f2bf(tacc[13] * 0.25f) << 16);
    o1.w = (unsigned)f2bf(tacc[14] * 0.25f) | ((unsigned)f2bf(tacc[15] * 0.25f) << 16);
    ((uint4*)tp)[0] = o0;
    ((uint4*)tp)[1] = o1;
}

extern "C" void kernel_launch(void* const* d_in, const int* in_sizes, int n_in,
                              void* d_out, int out_size, void* d_ws, size_t ws_size,
                              hipStream_t stream)
{
    const float* x   = (const float*)d_in[0];
    const int* esrc  = (const int*)d_in[1];
    const int* edst  = (const int*)d_in[2];
    const float* Wk  = (const float*)d_in[3];
    const float* bk  = (const float*)d_in[4];
    const float* Wq  = (const float*)d_in[5];
    const float* bq  = (const float*)d_in[6];
    const float* Wv  = (const float*)d_in[7];
    const float* bv  = (const float*)d_in[8];
    const float* Wa  = (const float*)d_in[9];
    const float* ba  = (const float*)d_in[10];
    const float* rel_att = (const float*)d_in[11];
    const float* rel_msg = (const float*)d_in[12];
    const float* rel_pri = (const float*)d_in[13];
    const float* skip    = (const float*)d_in[14];
    float* out = (float*)d_out;

    // ws (4B units): [t:ND2][q:ND2][k:ND2][vM:4*ND2][wAll:6*8192][bAll:768]
    //                [cnt:NSEG][dhist:1024][dcur:1024][offs:NSEG][cur:NSEG]
    //                [bsum:512][csr:NEDGE][deg:NN][order:NN]
    unsigned* wsu = (unsigned*)d_ws;
    unsigned* tbp = wsu;
    unsigned* qb  = tbp + ND2;
    unsigned* kb  = qb + ND2;
    unsigned* vMb = kb + ND2;
    unsigned* wAll = vMb + 4L * ND2;
    float* bAll = (float*)(wAll + 6 * WMAT);
    int* cnt   = (int*)(bAll + 768);
    int* dhist = cnt + NSEG;
    int* dcur  = dhist + 1024;
    int* offs  = dcur + 1024;
    int* cur   = offs + NSEG;
    int* bsum  = cur + NSEG;
    int* csr   = bsum + 512;
    int* deg   = csr + NEDGE;
    int* order = deg + NN;

    // zero cnt + dhist + dcur (contiguous)
    hipMemsetAsync(cnt, 0, (NSEG + 2048) * sizeof(int), stream);

    prep_pack<<<2, 256, 0, stream>>>(Wk, bk, Wq, bq, wAll, bAll);
    prep_wmsg<<<32, 128, 0, stream>>>(Wv, bv, rel_msg, wAll, bAll);

    const int gb = (NN + 63) / 64;   // 1563
    mfma_proj<<<dim3(gb, 3), 256, 0, stream>>>(x, wAll, bAll, kb, qb, vMb);

    const int ebk = (NEDGE + 255) / 256;
    csr_hist<<<ebk, 256, 0, stream>>>(edst, cnt);
    scan1<<<SCAN_NB, SCAN_BLK, 0, stream>>>(cnt, offs, bsum);
    scan2<<<1, 512, 0, stream>>>(bsum);
    scan3<<<SCAN_NB, SCAN_BLK, 0, stream>>>(offs, cur, bsum);
    csr_fill<<<ebk, 256, 0, stream>>>(esrc, edst, cur, csr);

    const int nbk = (NN + 255) / 256;
    deg_hist<<<nbk, 256, 0, stream>>>(offs, deg, dhist);
    deg_scan<<<1, 1024, 0, stream>>>(dhist, dcur);
    deg_fill<<<nbk, 256, 0, stream>>>(deg, dcur, order);

    gather_agg<<<(NN * HH + GT - 1) / GT, GT, 0, stream>>>(
        kb, qb, vMb, csr, offs, order, rel_att, rel_pri, tbp);

    mfma_out<<<gb, 256, 0, stream>>>(tbp, Wa, ba, out, skip, x);
}

// Round 15
// 422.369 us; speedup vs baseline: 2.4842x; 2.4842x over previous
//
#include <hip/hip_runtime.h>

#define NN 100000
#define DD 128
#define RR 4
#define EE 150000
#define HH 8
#define DK 16

#define NSEG (RR * NN)        // 400000
#define NEDGE (RR * EE)       // 600000
#define SCAN_BLK 256
#define SCAN_ELEMS 1024
#define SCAN_NB ((NSEG + SCAN_ELEMS - 1) / SCAN_ELEMS)   // 391
#define PAD_K 136             // bf16 row stride for MFMA LDS tiles
#define MAT_U 132             // uints per 16x16 bf16 matrix (528 B stride)
#define ND2 (NN * 64)         // uints per packed bf16 [node][128] buffer
#define WMAT 8192             // uints per packed 128x128 bf16 weight matrix
#define DBUCK 64              // degree buckets (clamped)
#define DNB ((NN + 255) / 256)  // 391 blocks for the degree sort

typedef short bf16x8 __attribute__((ext_vector_type(8)));
typedef float f32x4  __attribute__((ext_vector_type(4)));

// f32 -> bf16 round-to-nearest-even (bit pattern as ushort)
__device__ __forceinline__ unsigned short f2bf(float f) {
    unsigned u = __float_as_uint(f);
    return (unsigned short)((u + 0x7fffu + ((u >> 16) & 1u)) >> 16);
}
__device__ __forceinline__ float bflo(unsigned w) { return __uint_as_float(w << 16); }
__device__ __forceinline__ float bfhi(unsigned w) { return __uint_as_float(w & 0xffff0000u); }

// fragment-order swizzle for packed W: uint (n,c) -> position such that the
// wave-load of fragment (wc,j,ks) is lane-contiguous (fully coalesced).
__device__ __forceinline__ int wswz(int n, int c) {
    int ks = c >> 4, kg = (c >> 2) & 3, e = c & 3;
    int wc = n >> 6, j = (n >> 4) & 3, lrow = n & 15;
    return ((((ks * 2 + wc) * 4 + j) * 64) + kg * 16 + lrow) * 4 + e;
}

// ---------- prep: pack Wk, Wq to swizzled bf16; copy biases ----------
__global__ __launch_bounds__(256) void prep_pack(
    const float* __restrict__ Wk, const float* __restrict__ bk,
    const float* __restrict__ Wq, const float* __restrict__ bq,
    unsigned* __restrict__ wAll, float* __restrict__ bAll)
{
    const int b = blockIdx.x;   // 0: k, 1: q
    const float* W = b ? Wq : Wk;
    const float* bias = b ? bq : bk;
    unsigned* out = wAll + b * WMAT;
    const int tid = threadIdx.x;
    #pragma unroll
    for (int i = 0; i < 32; ++i) {
        int idx = tid + 256 * i;                    // 0..8191 = n*64 + c
        float2 v = *(const float2*)(W + idx * 2);
        unsigned u = (unsigned)f2bf(v.x) | ((unsigned)f2bf(v.y) << 16);
        out[wswz(idx >> 6, idx & 63)] = u;
    }
    if (tid < 128) bAll[b * 128 + tid] = bias[tid];
}

// ---------- prep: W_msg[r] = rel_msg-combined Wv (swizzled bf16), b_msg ----------
__global__ __launch_bounds__(128) void prep_wmsg(
    const float* __restrict__ Wv, const float* __restrict__ bv,
    const float* __restrict__ rel_msg,
    unsigned* __restrict__ wAll, float* __restrict__ bAll)
{
    const int b = blockIdx.x;          // r*8 + h
    const int r = b >> 3, h = b & 7;
    const int c = threadIdx.x;         // 0..127
    __shared__ float Msh[256];
    __shared__ float sh2[16][128];
    for (int i = c; i < 256; i += 128) Msh[i] = rel_msg[(b << 8) + i];
    __syncthreads();

    #pragma unroll 4
    for (int f = 0; f < 16; ++f) {
        float acc = 0.f;
        #pragma unroll
        for (int d = 0; d < 16; ++d)
            acc = __builtin_fmaf(Msh[d * 16 + f], Wv[(h * 16 + d) * DD + c], acc);
        sh2[f][c] = acc;
    }
    if (c < 16) {
        float acc = 0.f;
        #pragma unroll
        for (int d = 0; d < 16; ++d)
            acc = __builtin_fmaf(Msh[d * 16 + c], bv[h * 16 + d], acc);
        bAll[(2 + r) * 128 + h * 16 + c] = acc;
    }
    __syncthreads();

    unsigned* out = wAll + (2 + r) * WMAT;
    #pragma unroll
    for (int k = 0; k < 8; ++k) {
        int idx = c * 8 + k;            // 0..1023
        int f = idx >> 6, jc = idx & 63;
        unsigned u = (unsigned)f2bf(sh2[f][2 * jc]) | ((unsigned)f2bf(sh2[f][2 * jc + 1]) << 16);
        out[wswz(h * 16 + f, jc)] = u;
    }
}

// ---------- MFMA projections (grid.y = 3, TWO mats per block) ----------
__global__ __launch_bounds__(256) void mfma_proj(
    const float* __restrict__ X,
    const unsigned* __restrict__ wAll, const float* __restrict__ bAll,
    unsigned* __restrict__ kb, unsigned* __restrict__ qb, unsigned* __restrict__ vMb)
{
    const int tid = threadIdx.x;
    const int lane = tid & 63;
    const int wave = tid >> 6;
    const int wr = wave >> 1;            // X-row half (32 rows)
    const int wc = wave & 1;             // out-dim half (64 dims)
    const long m0 = (long)blockIdx.x * 64;
    const int mp = blockIdx.y * 2;       // first of the 2 mats

    __shared__ short Xs[64 * PAD_K];

    #pragma unroll
    for (int i = 0; i < 8; ++i) {
        int f = tid + 256 * i;
        int row = f >> 5, c4 = f & 31;
        long m = m0 + row;
        float4 v = make_float4(0.f, 0.f, 0.f, 0.f);
        if (m < NN) v = ((const float4*)(X + m * DD))[c4];
        unsigned u0 = (unsigned)f2bf(v.x) | ((unsigned)f2bf(v.y) << 16);
        unsigned u1 = (unsigned)f2bf(v.z) | ((unsigned)f2bf(v.w) << 16);
        *(uint2*)&Xs[row * PAD_K + c4 * 4] = make_uint2(u0, u1);
    }
    __syncthreads();

    const int lrow = lane & 15;
    const int kg = lane >> 4;            // 0..3

    #pragma unroll
    for (int mm = 0; mm < 2; ++mm) {
        const int mat = mp + mm;
        const unsigned* Wp = wAll + mat * WMAT;
        const float* bias = bAll + mat * 128;
        unsigned* outb = (mat == 0) ? kb : (mat == 1) ? qb : (vMb + (long)(mat - 2) * ND2);

        f32x4 acc[2][4];
        #pragma unroll
        for (int i = 0; i < 2; ++i)
            #pragma unroll
            for (int j = 0; j < 4; ++j) acc[i][j] = (f32x4){0.f, 0.f, 0.f, 0.f};

        #pragma unroll
        for (int ks = 0; ks < 4; ++ks) {
            const int kk = ks * 32 + kg * 8;
            bf16x8 xf[2], wf[4];
            #pragma unroll
            for (int i = 0; i < 2; ++i)
                xf[i] = *(const bf16x8*)&Xs[(wr * 32 + i * 16 + lrow) * PAD_K + kk];
            #pragma unroll
            for (int j = 0; j < 4; ++j)
                wf[j] = *(const bf16x8*)(Wp + (((ks * 2 + wc) * 4 + j) << 8) + (lane << 2));
            #pragma unroll
            for (int i = 0; i < 2; ++i)
                #pragma unroll
                for (int j = 0; j < 4; ++j)
                    acc[i][j] = __builtin_amdgcn_mfma_f32_16x16x32_bf16(wf[j], xf[i], acc[i][j], 0, 0, 0);
        }

        #pragma unroll
        for (int j = 0; j < 4; ++j) {
            const int nb = wc * 64 + j * 16 + kg * 4;
            const float b0 = bias[nb + 0], b1 = bias[nb + 1];
            const float b2 = bias[nb + 2], b3 = bias[nb + 3];
            #pragma unroll
            for (int i = 0; i < 2; ++i) {
                long m = m0 + wr * 32 + i * 16 + lrow;
                if (m < NN) {
                    unsigned u0 = (unsigned)f2bf(acc[i][j][0] + b0) | ((unsigned)f2bf(acc[i][j][1] + b1) << 16);
                    unsigned u1 = (unsigned)f2bf(acc[i][j][2] + b2) | ((unsigned)f2bf(acc[i][j][3] + b3) << 16);
                    *(uint2*)&outb[m * 64 + (nb >> 1)] = make_uint2(u0, u1);
                }
            }
        }
    }
}

// ---------- MFMA bf16 output GEMM: out = tb@Wa^T + ba, skip-gated ----------
__global__ __launch_bounds__(256) void mfma_out(
    const unsigned* __restrict__ Tp, const float* __restrict__ Wa, const float* __restrict__ ba,
    float* __restrict__ out, const float* __restrict__ skip, const float* __restrict__ xres)
{
    const int tid = threadIdx.x;
    const int lane = tid & 63;
    const int wave = tid >> 6;
    const int wr = wave >> 1;
    const int wc = wave & 1;
    const long m0 = (long)blockIdx.x * 64;

    __shared__ short Xs[64 * PAD_K];
    __shared__ short Wsh[128 * PAD_K];

    #pragma unroll
    for (int i = 0; i < 4; ++i) {
        int f = tid + 256 * i;            // uint4 slot in 64x16
        int row = f >> 4, c = f & 15;
        long m = m0 + row;
        uint4 v = make_uint4(0u, 0u, 0u, 0u);
        if (m < NN) v = ((const uint4*)(Tp + m * 64))[c];
        *(uint4*)&Xs[row * PAD_K + c * 8] = v;
    }
    #pragma unroll
    for (int i = 0; i < 16; ++i) {
        int f = tid + 256 * i;
        int row = f >> 5, c4 = f & 31;
        float4 v = ((const float4*)(Wa + row * DD))[c4];
        unsigned u0 = (unsigned)f2bf(v.x) | ((unsigned)f2bf(v.y) << 16);
        unsigned u1 = (unsigned)f2bf(v.z) | ((unsigned)f2bf(v.w) << 16);
        *(uint2*)&Wsh[row * PAD_K + c4 * 4] = make_uint2(u0, u1);
    }
    __syncthreads();

    const int lrow = lane & 15;
    const int kg = lane >> 4;

    f32x4 acc[2][4];
    #pragma unroll
    for (int i = 0; i < 2; ++i)
        #pragma unroll
        for (int j = 0; j < 4; ++j) acc[i][j] = (f32x4){0.f, 0.f, 0.f, 0.f};

    #pragma unroll
    for (int ks = 0; ks < 4; ++ks) {
        const int kk = ks * 32 + kg * 8;
        bf16x8 xf[2], wf[4];
        #pragma unroll
        for (int i = 0; i < 2; ++i)
            xf[i] = *(const bf16x8*)&Xs[(wr * 32 + i * 16 + lrow) * PAD_K + kk];
        #pragma unroll
        for (int j = 0; j < 4; ++j)
            wf[j] = *(const bf16x8*)&Wsh[(wc * 64 + j * 16 + lrow) * PAD_K + kk];
        #pragma unroll
        for (int i = 0; i < 2; ++i)
            #pragma unroll
            for (int j = 0; j < 4; ++j)
                acc[i][j] = __builtin_amdgcn_mfma_f32_16x16x32_bf16(xf[i], wf[j], acc[i][j], 0, 0, 0);
    }

    const float s = 1.f / (1.f + __expf(-skip[0]));
    const float al = s, bt = 1.f - s;

    #pragma unroll
    for (int j = 0; j < 4; ++j) {
        const int n = wc * 64 + j * 16 + lrow;
        const float bcol = ba[n];
        #pragma unroll
        for (int i = 0; i < 2; ++i) {
            #pragma unroll
            for (int r = 0; r < 4; ++r) {
                long m = m0 + wr * 32 + i * 16 + kg * 4 + r;
                if (m < NN) {
                    long o = m * DD + n;
                    out[o] = __builtin_fmaf(xres[o], bt, (acc[i][j][r] + bcol) * al);
                }
            }
        }
    }
}

// ---------- CSR build: histogram -> scan -> fill ----------

__global__ __launch_bounds__(256) void csr_hist(
    const int* __restrict__ edst, int* __restrict__ cnt)
{
    int idx = blockIdx.x * 256 + threadIdx.x;
    if (idx >= NEDGE) return;
    int r = idx / EE;
    atomicAdd(&cnt[r * NN + edst[idx]], 1);
}

__global__ __launch_bounds__(SCAN_BLK) void scan1(
    const int* __restrict__ cnt, int* __restrict__ offs, int* __restrict__ bsum)
{
    __shared__ int sh[SCAN_BLK];
    int blk = blockIdx.x, tid = threadIdx.x;
    int base = blk * SCAN_ELEMS + tid * 4;
    int v0 = 0, v1 = 0, v2 = 0, v3 = 0;
    if (base + 3 < NSEG) {
        int4 t = *(const int4*)(cnt + base);
        v0 = t.x; v1 = t.y; v2 = t.z; v3 = t.w;
    } else {
        if (base + 0 < NSEG) v0 = cnt[base + 0];
        if (base + 1 < NSEG) v1 = cnt[base + 1];
        if (base + 2 < NSEG) v2 = cnt[base + 2];
        if (base + 3 < NSEG) v3 = cnt[base + 3];
    }
    int tsum = v0 + v1 + v2 + v3;
    sh[tid] = tsum;
    __syncthreads();
    #pragma unroll
    for (int d = 1; d < SCAN_BLK; d <<= 1) {
        int x = (tid >= d) ? sh[tid - d] : 0;
        __syncthreads();
        sh[tid] += x;
        __syncthreads();
    }
    int excl = sh[tid] - tsum;
    int r0 = excl, r1 = r0 + v0, r2 = r1 + v1, r3 = r2 + v2;
    if (base + 3 < NSEG) {
        *(int4*)(offs + base) = make_int4(r0, r1, r2, r3);
    } else {
        if (base + 0 < NSEG) offs[base + 0] = r0;
        if (base + 1 < NSEG) offs[base + 1] = r1;
        if (base + 2 < NSEG) offs[base + 2] = r2;
        if (base + 3 < NSEG) offs[base + 3] = r3;
    }
    if (tid == SCAN_BLK - 1) bsum[blk] = sh[tid];
}

__global__ __launch_bounds__(512) void scan2(int* __restrict__ bsum)
{
    __shared__ int sh[512];
    int tid = threadIdx.x;
    int v = (tid < SCAN_NB) ? bsum[tid] : 0;
    sh[tid] = v;
    __syncthreads();
    #pragma unroll
    for (int d = 1; d < 512; d <<= 1) {
        int x = (tid >= d) ? sh[tid - d] : 0;
        __syncthreads();
        sh[tid] += x;
        __syncthreads();
    }
    if (tid < SCAN_NB) bsum[tid] = sh[tid] - v;
}

__global__ __launch_bounds__(SCAN_BLK) void scan3(
    int* __restrict__ offs, int* __restrict__ cur, const int* __restrict__ bsum)
{
    int blk = blockIdx.x;
    int add = bsum[blk];
    int base = blk * SCAN_ELEMS + threadIdx.x * 4;
    #pragma unroll
    for (int j = 0; j < 4; ++j)
        if (base + j < NSEG) {
            int v = offs[base + j] + add;
            offs[base + j] = v;
            cur[base + j] = v;
        }
}

__global__ __launch_bounds__(256) void csr_fill(
    const int* __restrict__ esrc, const int* __restrict__ edst,
    int* __restrict__ cur, int* __restrict__ csr_src)
{
    int idx = blockIdx.x * 256 + threadIdx.x;
    if (idx >= NEDGE) return;
    int r = idx / EE;
    int pos = atomicAdd(&cur[r * NN + edst[idx]], 1);
    csr_src[pos] = esrc[idx];
}

// ---------- degree counting-sort, CONTENTION-FREE (LDS hist + block offsets) ----------
// deg clamped to 63 (order correctness only needs a permutation; clamping
// just merges the tail buckets). No global atomics anywhere.
__global__ __launch_bounds__(256) void deg_hist(
    const int* __restrict__ offs, int* __restrict__ deg, int* __restrict__ blockHist)
{
    __shared__ int h[DBUCK];
    const int tid = threadIdx.x;
    if (tid < DBUCK) h[tid] = 0;
    __syncthreads();
    int i = blockIdx.x * 256 + tid;
    if (i < NN) {
        int d = 0;
        #pragma unroll
        for (int r = 0; r < RR; ++r) {
            int seg = r * NN + i;
            int beg = offs[seg];
            int end = (seg == NSEG - 1) ? NEDGE : offs[seg + 1];
            d += end - beg;
        }
        d = min(d, DBUCK - 1);
        deg[i] = d;
        atomicAdd(&h[d], 1);               // LDS atomic
    }
    __syncthreads();
    if (tid < DBUCK) blockHist[blockIdx.x * DBUCK + tid] = h[tid];
}

// single block: blockOff[b][d] = bucket-d base + sum_{b'<b} blockHist[b'][d]
__global__ __launch_bounds__(64) void deg_scan(
    const int* __restrict__ blockHist, int* __restrict__ blockOff)
{
    __shared__ int tot[DBUCK];
    __shared__ int base[DBUCK];
    const int d = threadIdx.x;             // one lane per bucket
    int run = 0;
    for (int b = 0; b < DNB; ++b) {
        blockOff[b * DBUCK + d] = run;
        run += blockHist[b * DBUCK + d];
    }
    tot[d] = run;
    __syncthreads();
    if (d == 0) {
        int r2 = 0;
        for (int k = 0; k < DBUCK; ++k) { base[k] = r2; r2 += tot[k]; }
    }
    __syncthreads();
    const int bd = base[d];
    for (int b = 0; b < DNB; ++b) blockOff[b * DBUCK + d] += bd;
}

__global__ __launch_bounds__(256) void deg_fill(
    const int* __restrict__ deg, const int* __restrict__ blockOff,
    int* __restrict__ order)
{
    __shared__ int h[DBUCK];
    const int tid = threadIdx.x;
    if (tid < DBUCK) h[tid] = 0;
    __syncthreads();
    int i = blockIdx.x * 256 + tid;
    if (i < NN) {
        int d = deg[i];
        int rank = atomicAdd(&h[d], 1);    // LDS atomic: rank within block
        order[blockOff[blockIdx.x * DBUCK + d] + rank] = i;
    }
}

// ---------- fused per-dst gather (degree-sorted dst order) ----------
#define GT 512
__global__ __launch_bounds__(GT) void gather_agg(
    const unsigned* __restrict__ kb, const unsigned* __restrict__ qbuf,
    const unsigned* __restrict__ vMb,
    const int* __restrict__ csr_src, const int* __restrict__ offs,
    const int* __restrict__ order,
    const float* __restrict__ rel_att, const float* __restrict__ rel_pri,
    unsigned* __restrict__ tb)
{
    __shared__ unsigned As[32 * MAT_U];
    __shared__ float prish[32];
    const int tid = threadIdx.x;
    #pragma unroll
    for (int i = 0; i < (32 * 128) / GT; ++i) {
        int f = tid + GT * i;
        int m = f >> 7, j = f & 127;
        float2 a = *(const float2*)(rel_att + m * 256 + j * 2);
        As[m * MAT_U + j] = (unsigned)f2bf(a.x) | ((unsigned)f2bf(a.y) << 16);
    }
    if (tid < 32) prish[tid] = rel_pri[tid] * 0.25f;
    __syncthreads();

    int gidx = blockIdx.x * GT + tid;
    if (gidx >= NN * HH) return;
    const int dst = order[gidx >> 3];
    const int h = gidx & 7;

    float qh[16];
    {
        const uint4* qp = (const uint4*)(qbuf + (long)dst * 64 + h * 8);
        uint4 qa = qp[0], qc = qp[1];
        qh[0] = bflo(qa.x);  qh[1] = bfhi(qa.x);
        qh[2] = bflo(qa.y);  qh[3] = bfhi(qa.y);
        qh[4] = bflo(qa.z);  qh[5] = bfhi(qa.z);
        qh[6] = bflo(qa.w);  qh[7] = bfhi(qa.w);
        qh[8] = bflo(qc.x);  qh[9] = bfhi(qc.x);
        qh[10] = bflo(qc.y); qh[11] = bfhi(qc.y);
        qh[12] = bflo(qc.z); qh[13] = bfhi(qc.z);
        qh[14] = bflo(qc.w); qh[15] = bfhi(qc.w);
    }

    float tacc[16];
    #pragma unroll
    for (int f = 0; f < 16; ++f) tacc[f] = 0.f;

    for (int r = 0; r < RR; ++r) {
        const int seg = r * NN + dst;
        const int beg = offs[seg];
        const int end = (seg == NSEG - 1) ? NEDGE : offs[seg + 1];
        if (end <= beg) continue;                 // empty mailbox contributes 0

        const unsigned* A = &As[(r * HH + h) * MAT_U];
        const float pri = prish[r * HH + h];

        float qbar[16];
        #pragma unroll
        for (int d = 0; d < 16; ++d) {
            uint4 r0 = *(const uint4*)&A[d * 8];
            uint4 r1 = *(const uint4*)&A[d * 8 + 4];
            float acc = bflo(r0.x) * qh[0];
            acc = __builtin_fmaf(bfhi(r0.x), qh[1], acc);
            acc = __builtin_fmaf(bflo(r0.y), qh[2], acc);
            acc = __builtin_fmaf(bfhi(r0.y), qh[3], acc);
            acc = __builtin_fmaf(bflo(r0.z), qh[4], acc);
            acc = __builtin_fmaf(bfhi(r0.z), qh[5], acc);
            acc = __builtin_fmaf(bflo(r0.w), qh[6], acc);
            acc = __builtin_fmaf(bfhi(r0.w), qh[7], acc);
            acc = __builtin_fmaf(bflo(r1.x), qh[8], acc);
            acc = __builtin_fmaf(bfhi(r1.x), qh[9], acc);
            acc = __builtin_fmaf(bflo(r1.y), qh[10], acc);
            acc = __builtin_fmaf(bfhi(r1.y), qh[11], acc);
            acc = __builtin_fmaf(bflo(r1.z), qh[12], acc);
            acc = __builtin_fmaf(bfhi(r1.z), qh[13], acc);
            acc = __builtin_fmaf(bflo(r1.w), qh[14], acc);
            acc = __builtin_fmaf(bfhi(r1.w), qh[15], acc);
            qbar[d] = acc * pri;
        }

        float s = 0.f;
        float vb[16];
        #pragma unroll
        for (int f = 0; f < 16; ++f) vb[f] = 0.f;

        const unsigned* vMr = vMb + (long)r * ND2;
        for (int e = beg; e < end; ++e) {
            int src = csr_src[e];
            const uint4* kp = (const uint4*)(kb + (long)src * 64 + h * 8);
            uint4 ka = kp[0], kc = kp[1];
            const uint4* vp = (const uint4*)(vMr + (long)src * 64 + h * 8);
            uint4 va = vp[0], vc = vp[1];

            float att;
            att  = bflo(ka.x) * qbar[0];
            att = __builtin_fmaf(bfhi(ka.x), qbar[1], att);
            att = __builtin_fmaf(bflo(ka.y), qbar[2], att);
            att = __builtin_fmaf(bfhi(ka.y), qbar[3], att);
            att = __builtin_fmaf(bflo(ka.z), qbar[4], att);
            att = __builtin_fmaf(bfhi(ka.z), qbar[5], att);
            att = __builtin_fmaf(bflo(ka.w), qbar[6], att);
            att = __builtin_fmaf(bfhi(ka.w), qbar[7], att);
            att = __builtin_fmaf(bflo(kc.x), qbar[8], att);
            att = __builtin_fmaf(bfhi(kc.x), qbar[9], att);
            att = __builtin_fmaf(bflo(kc.y), qbar[10], att);
            att = __builtin_fmaf(bfhi(kc.y), qbar[11], att);
            att = __builtin_fmaf(bflo(kc.z), qbar[12], att);
            att = __builtin_fmaf(bfhi(kc.z), qbar[13], att);
            att = __builtin_fmaf(bflo(kc.w), qbar[14], att);
            att = __builtin_fmaf(bfhi(kc.w), qbar[15], att);

            float ea = __expf(att);
            s += ea;
            vb[0]  = __builtin_fmaf(ea, bflo(va.x), vb[0]);
            vb[1]  = __builtin_fmaf(ea, bfhi(va.x), vb[1]);
            vb[2]  = __builtin_fmaf(ea, bflo(va.y), vb[2]);
            vb[3]  = __builtin_fmaf(ea, bfhi(va.y), vb[3]);
            vb[4]  = __builtin_fmaf(ea, bflo(va.z), vb[4]);
            vb[5]  = __builtin_fmaf(ea, bfhi(va.z), vb[5]);
            vb[6]  = __builtin_fmaf(ea, bflo(va.w), vb[6]);
            vb[7]  = __builtin_fmaf(ea, bfhi(va.w), vb[7]);
            vb[8]  = __builtin_fmaf(ea, bflo(vc.x), vb[8]);
            vb[9]  = __builtin_fmaf(ea, bfhi(vc.x), vb[9]);
            vb[10] = __builtin_fmaf(ea, bflo(vc.y), vb[10]);
            vb[11] = __builtin_fmaf(ea, bfhi(vc.y), vb[11]);
            vb[12] = __builtin_fmaf(ea, bflo(vc.z), vb[12]);
            vb[13] = __builtin_fmaf(ea, bfhi(vc.z), vb[13]);
            vb[14] = __builtin_fmaf(ea, bflo(vc.w), vb[14]);
            vb[15] = __builtin_fmaf(ea, bfhi(vc.w), vb[15]);
        }

        float inv = 1.f / s;
        #pragma unroll
        for (int f = 0; f < 16; ++f)
            tacc[f] = __builtin_fmaf(vb[f], inv, tacc[f]);
    }

    // write t packed bf16 with the cross-relation mean (x0.25, exact) folded
    unsigned* tp = tb + (long)dst * 64 + h * 8;
    uint4 o0, o1;
    o0.x = (unsigned)f2bf(tacc[0] * 0.25f)  | ((unsigned)f2bf(tacc[1] * 0.25f) << 16);
    o0.y = (unsigned)f2bf(tacc[2] * 0.25f)  | ((unsigned)f2bf(tacc[3] * 0.25f) << 16);
    o0.z = (unsigned)f2bf(tacc[4] * 0.25f)  | ((unsigned)f2bf(tacc[5] * 0.25f) << 16);
    o0.w = (unsigned)f2bf(tacc[6] * 0.25f)  | ((unsigned)f2bf(tacc[7] * 0.25f) << 16);
    o1.x = (unsigned)f2bf(tacc[8] * 0.25f)  | ((unsigned)f2bf(tacc[9] * 0.25f) << 16);
    o1.y = (unsigned)f2bf(tacc[10] * 0.25f) | ((unsigned)f2bf(tacc[11] * 0.25f) << 16);
    o1.z = (unsigned)f2bf(tacc[12] * 0.25f) | ((unsigned)f2bf(tacc[13] * 0.25f) << 16);
    o1.w = (unsigned)f2bf(tacc[14] * 0.25f) | ((unsigned)f2bf(tacc[15] * 0.25f) << 16);
    ((uint4*)tp)[0] = o0;
    ((uint4*)tp)[1] = o1;
}

extern "C" void kernel_launch(void* const* d_in, const int* in_sizes, int n_in,
                              void* d_out, int out_size, void* d_ws, size_t ws_size,
                              hipStream_t stream)
{
    const float* x   = (const float*)d_in[0];
    const int* esrc  = (const int*)d_in[1];
    const int* edst  = (const int*)d_in[2];
    const float* Wk  = (const float*)d_in[3];
    const float* bk  = (const float*)d_in[4];
    const float* Wq  = (const float*)d_in[5];
    const float* bq  = (const float*)d_in[6];
    const float* Wv  = (const float*)d_in[7];
    const float* bv  = (const float*)d_in[8];
    const float* Wa  = (const float*)d_in[9];
    const float* ba  = (const float*)d_in[10];
    const float* rel_att = (const float*)d_in[11];
    const float* rel_msg = (const float*)d_in[12];
    const float* rel_pri = (const float*)d_in[13];
    const float* skip    = (const float*)d_in[14];
    float* out = (float*)d_out;

    // ws (4B units): [t:ND2][q:ND2][k:ND2][vM:4*ND2][wAll:6*8192][bAll:768]
    //                [cnt:NSEG][offs:NSEG][cur:NSEG][bsum:512][csr:NEDGE]
    //                [deg:NN][order:NN][blockHist:DNB*64][blockOff:DNB*64]
    unsigned* wsu = (unsigned*)d_ws;
    unsigned* tbp = wsu;
    unsigned* qb  = tbp + ND2;
    unsigned* kb  = qb + ND2;
    unsigned* vMb = kb + ND2;
    unsigned* wAll = vMb + 4L * ND2;
    float* bAll = (float*)(wAll + 6 * WMAT);
    int* cnt   = (int*)(bAll + 768);
    int* offs  = cnt + NSEG;
    int* cur   = offs + NSEG;
    int* bsum  = cur + NSEG;
    int* csr   = bsum + 512;
    int* deg   = csr + NEDGE;
    int* order = deg + NN;
    int* blockHist = order + NN;
    int* blockOff  = blockHist + DNB * DBUCK;

    hipMemsetAsync(cnt, 0, NSEG * sizeof(int), stream);

    prep_pack<<<2, 256, 0, stream>>>(Wk, bk, Wq, bq, wAll, bAll);
    prep_wmsg<<<32, 128, 0, stream>>>(Wv, bv, rel_msg, wAll, bAll);

    const int gb = (NN + 63) / 64;   // 1563
    mfma_proj<<<dim3(gb, 3), 256, 0, stream>>>(x, wAll, bAll, kb, qb, vMb);

    const int ebk = (NEDGE + 255) / 256;
    csr_hist<<<ebk, 256, 0, stream>>>(edst, cnt);
    scan1<<<SCAN_NB, SCAN_BLK, 0, stream>>>(cnt, offs, bsum);
    scan2<<<1, 512, 0, stream>>>(bsum);
    scan3<<<SCAN_NB, SCAN_BLK, 0, stream>>>(offs, cur, bsum);
    csr_fill<<<ebk, 256, 0, stream>>>(esrc, edst, cur, csr);

    deg_hist<<<DNB, 256, 0, stream>>>(offs, deg, blockHist);
    deg_scan<<<1, 64, 0, stream>>>(blockHist, blockOff);
    deg_fill<<<DNB, 256, 0, stream>>>(deg, blockOff, order);

    gather_agg<<<(NN * HH + GT - 1) / GT, GT, 0, stream>>>(
        kb, qb, vMb, csr, offs, order, rel_att, rel_pri, tbp);

    mfma_out<<<gb, 256, 0, stream>>>(tbp, Wa, ba, out, skip, x);
}

// Round 16
// 306.990 us; speedup vs baseline: 3.4178x; 1.3758x over previous
//
#include <hip/hip_runtime.h>

#define NN 100000
#define DD 128
#define RR 4
#define EE 150000
#define HH 8
#define DK 16

#define NSEG (RR * NN)        // 400000
#define NEDGE (RR * EE)       // 600000
#define SCAN_BLK 256
#define SCAN_ELEMS 1024
#define SCAN_NB ((NSEG + SCAN_ELEMS - 1) / SCAN_ELEMS)   // 391
#define PAD_K 136             // bf16 row stride for MFMA LDS tiles
#define MAT_U 132             // uints per 16x16 bf16 matrix (528 B stride)
#define ND2 (NN * 64)         // uints per packed bf16 [node][128] buffer
#define WMAT 8192             // uints per packed 128x128 bf16 weight matrix

typedef short bf16x8 __attribute__((ext_vector_type(8)));
typedef float f32x4  __attribute__((ext_vector_type(4)));

// f32 -> bf16 round-to-nearest-even (bit pattern as ushort)
__device__ __forceinline__ unsigned short f2bf(float f) {
    unsigned u = __float_as_uint(f);
    return (unsigned short)((u + 0x7fffu + ((u >> 16) & 1u)) >> 16);
}
__device__ __forceinline__ float bflo(unsigned w) { return __uint_as_float(w << 16); }
__device__ __forceinline__ float bfhi(unsigned w) { return __uint_as_float(w & 0xffff0000u); }

// fragment-order swizzle for packed W: uint (n,c) -> position such that the
// wave-load of fragment (wc,j,ks) is lane-contiguous (fully coalesced).
__device__ __forceinline__ int wswz(int n, int c) {
    int ks = c >> 4, kg = (c >> 2) & 3, e = c & 3;
    int wc = n >> 6, j = (n >> 4) & 3, lrow = n & 15;
    return ((((ks * 2 + wc) * 4 + j) * 64) + kg * 16 + lrow) * 4 + e;
}

// ---------- prep: pack Wk, Wq to swizzled bf16; copy biases ----------
__global__ __launch_bounds__(256) void prep_pack(
    const float* __restrict__ Wk, const float* __restrict__ bk,
    const float* __restrict__ Wq, const float* __restrict__ bq,
    unsigned* __restrict__ wAll, float* __restrict__ bAll)
{
    const int b = blockIdx.x;   // 0: k, 1: q
    const float* W = b ? Wq : Wk;
    const float* bias = b ? bq : bk;
    unsigned* out = wAll + b * WMAT;
    const int tid = threadIdx.x;
    #pragma unroll
    for (int i = 0; i < 32; ++i) {
        int idx = tid + 256 * i;                    // 0..8191 = n*64 + c
        float2 v = *(const float2*)(W + idx * 2);
        unsigned u = (unsigned)f2bf(v.x) | ((unsigned)f2bf(v.y) << 16);
        out[wswz(idx >> 6, idx & 63)] = u;
    }
    if (tid < 128) bAll[b * 128 + tid] = bias[tid];
}

// ---------- prep: W_msg[r] = rel_msg-combined Wv (swizzled bf16), b_msg ----------
// W_msg[r][h*16+f][c] = sum_d M[r,h][d][f] * Wv[h*16+d][c]
__global__ __launch_bounds__(128) void prep_wmsg(
    const float* __restrict__ Wv, const float* __restrict__ bv,
    const float* __restrict__ rel_msg,
    unsigned* __restrict__ wAll, float* __restrict__ bAll)
{
    const int b = blockIdx.x;          // r*8 + h
    const int r = b >> 3, h = b & 7;
    const int c = threadIdx.x;         // 0..127
    __shared__ float Msh[256];
    __shared__ float sh2[16][128];
    for (int i = c; i < 256; i += 128) Msh[i] = rel_msg[(b << 8) + i];
    __syncthreads();

    #pragma unroll 4
    for (int f = 0; f < 16; ++f) {
        float acc = 0.f;
        #pragma unroll
        for (int d = 0; d < 16; ++d)
            acc = __builtin_fmaf(Msh[d * 16 + f], Wv[(h * 16 + d) * DD + c], acc);
        sh2[f][c] = acc;
    }
    if (c < 16) {
        float acc = 0.f;
        #pragma unroll
        for (int d = 0; d < 16; ++d)
            acc = __builtin_fmaf(Msh[d * 16 + c], bv[h * 16 + d], acc);
        bAll[(2 + r) * 128 + h * 16 + c] = acc;
    }
    __syncthreads();

    unsigned* out = wAll + (2 + r) * WMAT;
    #pragma unroll
    for (int k = 0; k < 8; ++k) {
        int idx = c * 8 + k;            // 0..1023
        int f = idx >> 6, jc = idx & 63;
        unsigned u = (unsigned)f2bf(sh2[f][2 * jc]) | ((unsigned)f2bf(sh2[f][2 * jc + 1]) << 16);
        out[wswz(h * 16 + f, jc)] = u;
    }
}

// ---------- MFMA projections (grid.y = 3, TWO mats per block) ----------
// Tile 64 X-rows. X staged bf16 in LDS once (17.4 KB, single barrier then
// read-only), amortized over 2 sequential GEMMs. W fragments loaded uint4
// from the SWIZZLED packed wAll (wave-load = 1 KB coalesced). Swapped
// operands: D = W*X^T so each lane holds 4 consecutive out-dims -> packed
// bf16 uint2 stores. mats: 0 k, 1 q, 2+r vM[r].
__global__ __launch_bounds__(256) void mfma_proj(
    const float* __restrict__ X,
    const unsigned* __restrict__ wAll, const float* __restrict__ bAll,
    unsigned* __restrict__ kb, unsigned* __restrict__ qb, unsigned* __restrict__ vMb)
{
    const int tid = threadIdx.x;
    const int lane = tid & 63;
    const int wave = tid >> 6;
    const int wr = wave >> 1;            // X-row half (32 rows)
    const int wc = wave & 1;             // out-dim half (64 dims)
    const long m0 = (long)blockIdx.x * 64;
    const int mp = blockIdx.y * 2;       // first of the 2 mats

    __shared__ short Xs[64 * PAD_K];

    #pragma unroll
    for (int i = 0; i < 8; ++i) {
        int f = tid + 256 * i;
        int row = f >> 5, c4 = f & 31;
        long m = m0 + row;
        float4 v = make_float4(0.f, 0.f, 0.f, 0.f);
        if (m < NN) v = ((const float4*)(X + m * DD))[c4];
        unsigned u0 = (unsigned)f2bf(v.x) | ((unsigned)f2bf(v.y) << 16);
        unsigned u1 = (unsigned)f2bf(v.z) | ((unsigned)f2bf(v.w) << 16);
        *(uint2*)&Xs[row * PAD_K + c4 * 4] = make_uint2(u0, u1);
    }
    __syncthreads();

    const int lrow = lane & 15;
    const int kg = lane >> 4;            // 0..3

    #pragma unroll
    for (int mm = 0; mm < 2; ++mm) {
        const int mat = mp + mm;
        const unsigned* Wp = wAll + mat * WMAT;
        const float* bias = bAll + mat * 128;
        unsigned* outb = (mat == 0) ? kb : (mat == 1) ? qb : (vMb + (long)(mat - 2) * ND2);

        f32x4 acc[2][4];
        #pragma unroll
        for (int i = 0; i < 2; ++i)
            #pragma unroll
            for (int j = 0; j < 4; ++j) acc[i][j] = (f32x4){0.f, 0.f, 0.f, 0.f};

        #pragma unroll
        for (int ks = 0; ks < 4; ++ks) {
            const int kk = ks * 32 + kg * 8;
            bf16x8 xf[2], wf[4];
            #pragma unroll
            for (int i = 0; i < 2; ++i)
                xf[i] = *(const bf16x8*)&Xs[(wr * 32 + i * 16 + lrow) * PAD_K + kk];
            #pragma unroll
            for (int j = 0; j < 4; ++j)
                wf[j] = *(const bf16x8*)(Wp + (((ks * 2 + wc) * 4 + j) << 8) + (lane << 2));
            #pragma unroll
            for (int i = 0; i < 2; ++i)
                #pragma unroll
                for (int j = 0; j < 4; ++j)
                    acc[i][j] = __builtin_amdgcn_mfma_f32_16x16x32_bf16(wf[j], xf[i], acc[i][j], 0, 0, 0);
        }

        #pragma unroll
        for (int j = 0; j < 4; ++j) {
            const int nb = wc * 64 + j * 16 + kg * 4;
            const float b0 = bias[nb + 0], b1 = bias[nb + 1];
            const float b2 = bias[nb + 2], b3 = bias[nb + 3];
            #pragma unroll
            for (int i = 0; i < 2; ++i) {
                long m = m0 + wr * 32 + i * 16 + lrow;
                if (m < NN) {
                    unsigned u0 = (unsigned)f2bf(acc[i][j][0] + b0) | ((unsigned)f2bf(acc[i][j][1] + b1) << 16);
                    unsigned u1 = (unsigned)f2bf(acc[i][j][2] + b2) | ((unsigned)f2bf(acc[i][j][3] + b3) << 16);
                    *(uint2*)&outb[m * 64 + (nb >> 1)] = make_uint2(u0, u1);
                }
            }
        }
    }
}

// ---------- MFMA bf16 output GEMM: out = tb@Wa^T + ba, skip-gated ----------
// tb is packed bf16 (0.25 already folded by gather) -> staging is a pure copy.
__global__ __launch_bounds__(256) void mfma_out(
    const unsigned* __restrict__ Tp, const float* __restrict__ Wa, const float* __restrict__ ba,
    float* __restrict__ out, const float* __restrict__ skip, const float* __restrict__ xres)
{
    const int tid = threadIdx.x;
    const int lane = tid & 63;
    const int wave = tid >> 6;
    const int wr = wave >> 1;
    const int wc = wave & 1;
    const long m0 = (long)blockIdx.x * 64;

    __shared__ short Xs[64 * PAD_K];
    __shared__ short Wsh[128 * PAD_K];

    #pragma unroll
    for (int i = 0; i < 4; ++i) {
        int f = tid + 256 * i;            // uint4 slot in 64x16
        int row = f >> 4, c = f & 15;
        long m = m0 + row;
        uint4 v = make_uint4(0u, 0u, 0u, 0u);
        if (m < NN) v = ((const uint4*)(Tp + m * 64))[c];
        *(uint4*)&Xs[row * PAD_K + c * 8] = v;
    }
    #pragma unroll
    for (int i = 0; i < 16; ++i) {
        int f = tid + 256 * i;
        int row = f >> 5, c4 = f & 31;
        float4 v = ((const float4*)(Wa + row * DD))[c4];
        unsigned u0 = (unsigned)f2bf(v.x) | ((unsigned)f2bf(v.y) << 16);
        unsigned u1 = (unsigned)f2bf(v.z) | ((unsigned)f2bf(v.w) << 16);
        *(uint2*)&Wsh[row * PAD_K + c4 * 4] = make_uint2(u0, u1);
    }
    __syncthreads();

    const int lrow = lane & 15;
    const int kg = lane >> 4;

    f32x4 acc[2][4];
    #pragma unroll
    for (int i = 0; i < 2; ++i)
        #pragma unroll
        for (int j = 0; j < 4; ++j) acc[i][j] = (f32x4){0.f, 0.f, 0.f, 0.f};

    #pragma unroll
    for (int ks = 0; ks < 4; ++ks) {
        const int kk = ks * 32 + kg * 8;
        bf16x8 xf[2], wf[4];
        #pragma unroll
        for (int i = 0; i < 2; ++i)
            xf[i] = *(const bf16x8*)&Xs[(wr * 32 + i * 16 + lrow) * PAD_K + kk];
        #pragma unroll
        for (int j = 0; j < 4; ++j)
            wf[j] = *(const bf16x8*)&Wsh[(wc * 64 + j * 16 + lrow) * PAD_K + kk];
        #pragma unroll
        for (int i = 0; i < 2; ++i)
            #pragma unroll
            for (int j = 0; j < 4; ++j)
                acc[i][j] = __builtin_amdgcn_mfma_f32_16x16x32_bf16(xf[i], wf[j], acc[i][j], 0, 0, 0);
    }

    const float s = 1.f / (1.f + __expf(-skip[0]));
    const float al = s, bt = 1.f - s;

    #pragma unroll
    for (int j = 0; j < 4; ++j) {
        const int n = wc * 64 + j * 16 + lrow;
        const float bcol = ba[n];
        #pragma unroll
        for (int i = 0; i < 2; ++i) {
            #pragma unroll
            for (int r = 0; r < 4; ++r) {
                long m = m0 + wr * 32 + i * 16 + kg * 4 + r;
                if (m < NN) {
                    long o = m * DD + n;
                    out[o] = __builtin_fmaf(xres[o], bt, (acc[i][j][r] + bcol) * al);
                }
            }
        }
    }
}

// ---------- CSR build: histogram -> scan -> fill ----------

__global__ __launch_bounds__(256) void csr_hist(
    const int* __restrict__ edst, int* __restrict__ cnt)
{
    int idx = blockIdx.x * 256 + threadIdx.x;
    if (idx >= NEDGE) return;
    int r = idx / EE;
    atomicAdd(&cnt[r * NN + edst[idx]], 1);
}

__global__ __launch_bounds__(SCAN_BLK) void scan1(
    const int* __restrict__ cnt, int* __restrict__ offs, int* __restrict__ bsum)
{
    __shared__ int sh[SCAN_BLK];
    int blk = blockIdx.x, tid = threadIdx.x;
    int base = blk * SCAN_ELEMS + tid * 4;
    int v0 = 0, v1 = 0, v2 = 0, v3 = 0;
    if (base + 3 < NSEG) {
        int4 t = *(const int4*)(cnt + base);
        v0 = t.x; v1 = t.y; v2 = t.z; v3 = t.w;
    } else {
        if (base + 0 < NSEG) v0 = cnt[base + 0];
        if (base + 1 < NSEG) v1 = cnt[base + 1];
        if (base + 2 < NSEG) v2 = cnt[base + 2];
        if (base + 3 < NSEG) v3 = cnt[base + 3];
    }
    int tsum = v0 + v1 + v2 + v3;
    sh[tid] = tsum;
    __syncthreads();
    #pragma unroll
    for (int d = 1; d < SCAN_BLK; d <<= 1) {
        int x = (tid >= d) ? sh[tid - d] : 0;
        __syncthreads();
        sh[tid] += x;
        __syncthreads();
    }
    int excl = sh[tid] - tsum;
    int r0 = excl, r1 = r0 + v0, r2 = r1 + v1, r3 = r2 + v2;
    if (base + 3 < NSEG) {
        *(int4*)(offs + base) = make_int4(r0, r1, r2, r3);
    } else {
        if (base + 0 < NSEG) offs[base + 0] = r0;
        if (base + 1 < NSEG) offs[base + 1] = r1;
        if (base + 2 < NSEG) offs[base + 2] = r2;
        if (base + 3 < NSEG) offs[base + 3] = r3;
    }
    if (tid == SCAN_BLK - 1) bsum[blk] = sh[tid];
}

__global__ __launch_bounds__(512) void scan2(int* __restrict__ bsum)
{
    __shared__ int sh[512];
    int tid = threadIdx.x;
    int v = (tid < SCAN_NB) ? bsum[tid] : 0;
    sh[tid] = v;
    __syncthreads();
    #pragma unroll
    for (int d = 1; d < 512; d <<= 1) {
        int x = (tid >= d) ? sh[tid - d] : 0;
        __syncthreads();
        sh[tid] += x;
        __syncthreads();
    }
    if (tid < SCAN_NB) bsum[tid] = sh[tid] - v;
}

__global__ __launch_bounds__(SCAN_BLK) void scan3(
    int* __restrict__ offs, int* __restrict__ cur, const int* __restrict__ bsum)
{
    int blk = blockIdx.x;
    int add = bsum[blk];
    int base = blk * SCAN_ELEMS + threadIdx.x * 4;
    #pragma unroll
    for (int j = 0; j < 4; ++j)
        if (base + j < NSEG) {
            int v = offs[base + j] + add;
            offs[base + j] = v;
            cur[base + j] = v;
        }
}

__global__ __launch_bounds__(256) void csr_fill(
    const int* __restrict__ esrc, const int* __restrict__ edst,
    int* __restrict__ cur, int* __restrict__ csr_src)
{
    int idx = blockIdx.x * 256 + threadIdx.x;
    if (idx >= NEDGE) return;
    int r = idx / EE;
    int pos = atomicAdd(&cur[r * NN + edst[idx]], 1);
    csr_src[pos] = esrc[idx];
}

// ---------- fused per-dst gather ----------
// thread = (dst,h). A (rel_att) staged bf16 in LDS (16.9 KB) + pri.
// Per relation: qbar = A@q (pri folded) once; edge loop reads k 32B + vM 32B;
// vb accumulates exp(att)*vM directly. t written PACKED bf16 (0.25 folded).
#define GT 512
__global__ __launch_bounds__(GT) void gather_agg(
    const unsigned* __restrict__ kb, const unsigned* __restrict__ qbuf,
    const unsigned* __restrict__ vMb,
    const int* __restrict__ csr_src, const int* __restrict__ offs,
    const float* __restrict__ rel_att, const float* __restrict__ rel_pri,
    unsigned* __restrict__ tb)
{
    __shared__ unsigned As[32 * MAT_U];
    __shared__ float prish[32];
    const int tid = threadIdx.x;
    #pragma unroll
    for (int i = 0; i < (32 * 128) / GT; ++i) {
        int f = tid + GT * i;
        int m = f >> 7, j = f & 127;
        float2 a = *(const float2*)(rel_att + m * 256 + j * 2);
        As[m * MAT_U + j] = (unsigned)f2bf(a.x) | ((unsigned)f2bf(a.y) << 16);
    }
    if (tid < 32) prish[tid] = rel_pri[tid] * 0.25f;
    __syncthreads();

    int gidx = blockIdx.x * GT + tid;
    if (gidx >= NN * HH) return;
    const int dst = gidx >> 3, h = gidx & 7;

    float qh[16];
    {
        const uint4* qp = (const uint4*)(qbuf + (long)dst * 64 + h * 8);
        uint4 qa = qp[0], qc = qp[1];
        qh[0] = bflo(qa.x);  qh[1] = bfhi(qa.x);
        qh[2] = bflo(qa.y);  qh[3] = bfhi(qa.y);
        qh[4] = bflo(qa.z);  qh[5] = bfhi(qa.z);
        qh[6] = bflo(qa.w);  qh[7] = bfhi(qa.w);
        qh[8] = bflo(qc.x);  qh[9] = bfhi(qc.x);
        qh[10] = bflo(qc.y); qh[11] = bfhi(qc.y);
        qh[12] = bflo(qc.z); qh[13] = bfhi(qc.z);
        qh[14] = bflo(qc.w); qh[15] = bfhi(qc.w);
    }

    float tacc[16];
    #pragma unroll
    for (int f = 0; f < 16; ++f) tacc[f] = 0.f;

    for (int r = 0; r < RR; ++r) {
        const int seg = r * NN + dst;
        const int beg = offs[seg];
        const int end = (seg == NSEG - 1) ? NEDGE : offs[seg + 1];
        if (end <= beg) continue;                 // empty mailbox contributes 0

        const unsigned* A = &As[(r * HH + h) * MAT_U];
        const float pri = prish[r * HH + h];

        float qbar[16];
        #pragma unroll
        for (int d = 0; d < 16; ++d) {
            uint4 r0 = *(const uint4*)&A[d * 8];
            uint4 r1 = *(const uint4*)&A[d * 8 + 4];
            float acc = bflo(r0.x) * qh[0];
            acc = __builtin_fmaf(bfhi(r0.x), qh[1], acc);
            acc = __builtin_fmaf(bflo(r0.y), qh[2], acc);
            acc = __builtin_fmaf(bfhi(r0.y), qh[3], acc);
            acc = __builtin_fmaf(bflo(r0.z), qh[4], acc);
            acc = __builtin_fmaf(bfhi(r0.z), qh[5], acc);
            acc = __builtin_fmaf(bflo(r0.w), qh[6], acc);
            acc = __builtin_fmaf(bfhi(r0.w), qh[7], acc);
            acc = __builtin_fmaf(bflo(r1.x), qh[8], acc);
            acc = __builtin_fmaf(bfhi(r1.x), qh[9], acc);
            acc = __builtin_fmaf(bflo(r1.y), qh[10], acc);
            acc = __builtin_fmaf(bfhi(r1.y), qh[11], acc);
            acc = __builtin_fmaf(bflo(r1.z), qh[12], acc);
            acc = __builtin_fmaf(bfhi(r1.z), qh[13], acc);
            acc = __builtin_fmaf(bflo(r1.w), qh[14], acc);
            acc = __builtin_fmaf(bfhi(r1.w), qh[15], acc);
            qbar[d] = acc * pri;
        }

        float s = 0.f;
        float vb[16];
        #pragma unroll
        for (int f = 0; f < 16; ++f) vb[f] = 0.f;

        const unsigned* vMr = vMb + (long)r * ND2;
        for (int e = beg; e < end; ++e) {
            int src = csr_src[e];
            const uint4* kp = (const uint4*)(kb + (long)src * 64 + h * 8);
            uint4 ka = kp[0], kc = kp[1];
            const uint4* vp = (const uint4*)(vMr + (long)src * 64 + h * 8);
            uint4 va = vp[0], vc = vp[1];

            float att;
            att  = bflo(ka.x) * qbar[0];
            att = __builtin_fmaf(bfhi(ka.x), qbar[1], att);
            att = __builtin_fmaf(bflo(ka.y), qbar[2], att);
            att = __builtin_fmaf(bfhi(ka.y), qbar[3], att);
            att = __builtin_fmaf(bflo(ka.z), qbar[4], att);
            att = __builtin_fmaf(bfhi(ka.z), qbar[5], att);
            att = __builtin_fmaf(bflo(ka.w), qbar[6], att);
            att = __builtin_fmaf(bfhi(ka.w), qbar[7], att);
            att = __builtin_fmaf(bflo(kc.x), qbar[8], att);
            att = __builtin_fmaf(bfhi(kc.x), qbar[9], att);
            att = __builtin_fmaf(bflo(kc.y), qbar[10], att);
            att = __builtin_fmaf(bfhi(kc.y), qbar[11], att);
            att = __builtin_fmaf(bflo(kc.z), qbar[12], att);
            att = __builtin_fmaf(bfhi(kc.z), qbar[13], att);
            att = __builtin_fmaf(bflo(kc.w), qbar[14], att);
            att = __builtin_fmaf(bfhi(kc.w), qbar[15], att);

            float ea = __expf(att);
            s += ea;
            vb[0]  = __builtin_fmaf(ea, bflo(va.x), vb[0]);
            vb[1]  = __builtin_fmaf(ea, bfhi(va.x), vb[1]);
            vb[2]  = __builtin_fmaf(ea, bflo(va.y), vb[2]);
            vb[3]  = __builtin_fmaf(ea, bfhi(va.y), vb[3]);
            vb[4]  = __builtin_fmaf(ea, bflo(va.z), vb[4]);
            vb[5]  = __builtin_fmaf(ea, bfhi(va.z), vb[5]);
            vb[6]  = __builtin_fmaf(ea, bflo(va.w), vb[6]);
            vb[7]  = __builtin_fmaf(ea, bfhi(va.w), vb[7]);
            vb[8]  = __builtin_fmaf(ea, bflo(vc.x), vb[8]);
            vb[9]  = __builtin_fmaf(ea, bfhi(vc.x), vb[9]);
            vb[10] = __builtin_fmaf(ea, bflo(vc.y), vb[10]);
            vb[11] = __builtin_fmaf(ea, bfhi(vc.y), vb[11]);
            vb[12] = __builtin_fmaf(ea, bflo(vc.z), vb[12]);
            vb[13] = __builtin_fmaf(ea, bfhi(vc.z), vb[13]);
            vb[14] = __builtin_fmaf(ea, bflo(vc.w), vb[14]);
            vb[15] = __builtin_fmaf(ea, bfhi(vc.w), vb[15]);
        }

        float inv = 1.f / s;
        #pragma unroll
        for (int f = 0; f < 16; ++f)
            tacc[f] = __builtin_fmaf(vb[f], inv, tacc[f]);
    }

    // write t packed bf16 with the cross-relation mean (x0.25, exact) folded
    unsigned* tp = tb + (long)dst * 64 + h * 8;
    uint4 o0, o1;
    o0.x = (unsigned)f2bf(tacc[0] * 0.25f)  | ((unsigned)f2bf(tacc[1] * 0.25f) << 16);
    o0.y = (unsigned)f2bf(tacc[2] * 0.25f)  | ((unsigned)f2bf(tacc[3] * 0.25f) << 16);
    o0.z = (unsigned)f2bf(tacc[4] * 0.25f)  | ((unsigned)f2bf(tacc[5] * 0.25f) << 16);
    o0.w = (unsigned)f2bf(tacc[6] * 0.25f)  | ((unsigned)f2bf(tacc[7] * 0.25f) << 16);
    o1.x = (unsigned)f2bf(tacc[8] * 0.25f)  | ((unsigned)f2bf(tacc[9] * 0.25f) << 16);
    o1.y = (unsigned)f2bf(tacc[10] * 0.25f) | ((unsigned)f2bf(tacc[11] * 0.25f) << 16);
    o1.z = (unsigned)f2bf(tacc[12] * 0.25f) | ((unsigned)f2bf(tacc[13] * 0.25f) << 16);
    o1.w = (unsigned)f2bf(tacc[14] * 0.25f) | ((unsigned)f2bf(tacc[15] * 0.25f) << 16);
    ((uint4*)tp)[0] = o0;
    ((uint4*)tp)[1] = o1;
}

extern "C" void kernel_launch(void* const* d_in, const int* in_sizes, int n_in,
                              void* d_out, int out_size, void* d_ws, size_t ws_size,
                              hipStream_t stream)
{
    const float* x   = (const float*)d_in[0];
    const int* esrc  = (const int*)d_in[1];
    const int* edst  = (const int*)d_in[2];
    const float* Wk  = (const float*)d_in[3];
    const float* bk  = (const float*)d_in[4];
    const float* Wq  = (const float*)d_in[5];
    const float* bq  = (const float*)d_in[6];
    const float* Wv  = (const float*)d_in[7];
    const float* bv  = (const float*)d_in[8];
    const float* Wa  = (const float*)d_in[9];
    const float* ba  = (const float*)d_in[10];
    const float* rel_att = (const float*)d_in[11];
    const float* rel_msg = (const float*)d_in[12];
    const float* rel_pri = (const float*)d_in[13];
    const float* skip    = (const float*)d_in[14];
    float* out = (float*)d_out;

    // ws (4B units): [t:ND2][q:ND2][k:ND2][vM:4*ND2][wAll:6*8192][bAll:768]
    //                [cnt:NSEG][offs:NSEG][cur:NSEG][bsum:512][csr:NEDGE]
    unsigned* wsu = (unsigned*)d_ws;
    unsigned* tbp = wsu;
    unsigned* qb  = tbp + ND2;
    unsigned* kb  = qb + ND2;
    unsigned* vMb = kb + ND2;
    unsigned* wAll = vMb + 4L * ND2;
    float* bAll = (float*)(wAll + 6 * WMAT);
    int* cnt  = (int*)(bAll + 768);
    int* offs = cnt + NSEG;
    int* cur  = offs + NSEG;
    int* bsum = cur + NSEG;
    int* csr  = bsum + 512;

    hipMemsetAsync(cnt, 0, NSEG * sizeof(int), stream);

    prep_pack<<<2, 256, 0, stream>>>(Wk, bk, Wq, bq, wAll, bAll);
    prep_wmsg<<<32, 128, 0, stream>>>(Wv, bv, rel_msg, wAll, bAll);

    const int gb = (NN + 63) / 64;   // 1563
    mfma_proj<<<dim3(gb, 3), 256, 0, stream>>>(x, wAll, bAll, kb, qb, vMb);

    const int ebk = (NEDGE + 255) / 256;
    csr_hist<<<ebk, 256, 0, stream>>>(edst, cnt);
    scan1<<<SCAN_NB, SCAN_BLK, 0, stream>>>(cnt, offs, bsum);
    scan2<<<1, 512, 0, stream>>>(bsum);
    scan3<<<SCAN_NB, SCAN_BLK, 0, stream>>>(offs, cur, bsum);
    csr_fill<<<ebk, 256, 0, stream>>>(esrc, edst, cur, csr);

    gather_agg<<<(NN * HH + GT - 1) / GT, GT, 0, stream>>>(
        kb, qb, vMb, csr, offs, rel_att, rel_pri, tbp);

    mfma_out<<<gb, 256, 0, stream>>>(tbp, Wa, ba, out, skip, x);
}